// Round 1
// baseline (244.512 us; speedup 1.0000x reference)
//
#include <hip/hip_runtime.h>
#include <hip/hip_bf16.h>

#define BB 64
#define SS 4096
#define EE 128   // EMB_DIM
#define DD 128   // DEC_DIM
#define FAN 256
#define NEG_INF_F (-1e10f)

typedef __bf16 bf16x8 __attribute__((ext_vector_type(8)));
typedef unsigned short u16x8 __attribute__((ext_vector_type(8)));
typedef float f32x4 __attribute__((ext_vector_type(4)));

__device__ inline unsigned short f2bf(float f) {
    union { float f; unsigned u; } v; v.f = f;
    unsigned r = v.u + 0x7FFFu + ((v.u >> 16) & 1u);   // RNE, matches HW cvt
    return (unsigned short)(r >> 16);
}

__device__ inline bf16x8 ld_frag(const unsigned short* p) {
    union { u16x8 u; bf16x8 b; } c;
    c.u = *(const u16x8*)p;
    return c.b;
}

__device__ inline float tanh_fast(float x) {
    float ax = fabsf(x);
    float e = __expf(-2.0f * ax);
    float t = (1.0f - e) * __builtin_amdgcn_rcpf(1.0f + e);
    return x < 0.0f ? -t : t;
}

// ---------------------------------------------------------------------------
// Kernel 1: h_proj (fp32) + We -> bf16 conversion + v copy, into workspace.
// grid 64 x 256
// ---------------------------------------------------------------------------
__global__ __launch_bounds__(256) void prep_kernel(
        const float* __restrict__ hidden, const float* __restrict__ W_attn,
        const float* __restrict__ b_attn, const float* __restrict__ v_w,
        float* __restrict__ hproj, unsigned short* __restrict__ Wb,
        float* __restrict__ v_out) {
    const int b = blockIdx.x;
    const int t = threadIdx.x;
    if (t < 128) {
        // h_proj[b][t] = b_attn[t] + hidden[b,:] . W_attn[t, 0:128]
        float acc = b_attn[t];
        const float* hrow = hidden + b * DD;
        const float* wrow = W_attn + t * FAN;
        #pragma unroll 8
        for (int e = 0; e < DD; e++) acc += hrow[e] * wrow[e];
        hproj[b * DD + t] = acc;
        if (b == 0) v_out[t] = v_w[t];
    } else {
        // convert 2 rows of We per block (128 rows over 64 blocks)
        int tt = t - 128;
        int d  = 2 * b + (tt >> 6);
        int e0 = (tt & 63) * 2;
        const float* src = W_attn + d * FAN + DD + e0;
        Wb[d * EE + e0]     = f2bf(src[0]);
        Wb[d * EE + e0 + 1] = f2bf(src[1]);
    }
}

// ---------------------------------------------------------------------------
// Kernel 2: logits[b][s] = v . tanh(hproj[b] + X[s] @ We^T), masked.
// grid (S/64, B) x 256. Masked s-rows: skip the HBM read entirely.
// ---------------------------------------------------------------------------
__global__ __launch_bounds__(256) void logits_kernel(
        const float* __restrict__ seq_embs, const int* __restrict__ mask,
        const float* __restrict__ hproj, const unsigned short* __restrict__ Wb,
        const float* __restrict__ v, float* __restrict__ logits) {
    __shared__ __attribute__((aligned(16))) unsigned short Xs[64][136];  // s x e (pad: 136)
    __shared__ __attribute__((aligned(16))) unsigned short Ws[128][136]; // d x e (pad: 136)
    __shared__ int   mrow[64];
    __shared__ float hp_s[128];
    __shared__ float v_s[128];

    const int b   = blockIdx.y;
    const int s0  = blockIdx.x * 64;
    const int tid = threadIdx.x;

    if (tid < 64) {
        mrow[tid] = mask[b * SS + s0 + tid];
    } else if (tid < 192) {
        hp_s[tid - 64] = hproj[b * DD + (tid - 64)];
    } else {
        v_s[tid - 192]      = v[tid - 192];
        v_s[tid - 192 + 64] = v[tid - 192 + 64];
    }
    __syncthreads();

    // Stage We (bf16, from ws; L2-resident) into LDS [d][e]
    const ushort4* Wb4 = (const ushort4*)Wb;
    #pragma unroll
    for (int i = tid; i < 128 * 32; i += 256) {
        int d = i >> 5, e4 = i & 31;
        ushort4 w = Wb4[d * 32 + e4];
        *(ushort4*)&Ws[d][e4 * 4] = w;
    }

    // Stage X tile (64 s-rows), converting fp32->bf16; skip masked rows.
    #pragma unroll
    for (int i = tid; i < 64 * 32; i += 256) {
        int s = i >> 5, e4 = i & 31;
        ushort4 o;
        if (mrow[s] != 0) {
            const float4 f = *(const float4*)(seq_embs +
                    (size_t)(s0 + s) * (BB * EE) + (size_t)b * EE + e4 * 4);
            o.x = f2bf(f.x); o.y = f2bf(f.y); o.z = f2bf(f.z); o.w = f2bf(f.w);
        } else {
            o.x = 0; o.y = 0; o.z = 0; o.w = 0;
        }
        *(ushort4*)&Xs[s][e4 * 4] = o;
    }
    __syncthreads();

    const int wave = tid >> 6;
    const int lane = tid & 63;
    const int m    = lane & 15;
    const int quad = lane >> 4;

    f32x4 acc[8];
    #pragma unroll
    for (int t = 0; t < 8; t++) acc[t] = (f32x4){0.f, 0.f, 0.f, 0.f};

    const int arow = wave * 16 + m;
    #pragma unroll
    for (int kk = 0; kk < 4; kk++) {
        const int k0 = kk * 32 + quad * 8;
        bf16x8 a = ld_frag(&Xs[arow][k0]);
        #pragma unroll
        for (int t = 0; t < 8; t++) {
            bf16x8 bf = ld_frag(&Ws[t * 16 + m][k0]);
            acc[t] = __builtin_amdgcn_mfma_f32_16x16x32_bf16(a, bf, acc[t], 0, 0, 0);
        }
    }

    // Epilogue: logit[s] = sum_d v[d] * tanh(hp[d] + E[s][d])
    // D layout: row = quad*4 + r (s within wave tile), col = m (d within 16-tile)
    float red[4];
    #pragma unroll
    for (int r = 0; r < 4; r++) {
        float part = 0.f;
        #pragma unroll
        for (int t = 0; t < 8; t++) {
            int d = t * 16 + m;
            part += v_s[d] * tanh_fast(hp_s[d] + acc[t][r]);
        }
        part += __shfl_xor(part, 1);
        part += __shfl_xor(part, 2);
        part += __shfl_xor(part, 4);
        part += __shfl_xor(part, 8);
        red[r] = part;
    }
    if (m == 0) {
        #pragma unroll
        for (int r = 0; r < 4; r++) {
            int sl = wave * 16 + quad * 4 + r;
            float val = (mrow[sl] != 0) ? red[r] : NEG_INF_F;
            logits[(size_t)b * SS + s0 + sl] = val;
        }
    }
}

// ---------------------------------------------------------------------------
// Kernel 3: in-place row softmax over S=4096. grid B x 256.
// ---------------------------------------------------------------------------
__global__ __launch_bounds__(256) void softmax_kernel(float* __restrict__ logits) {
    const int b = blockIdx.x;
    const int tid = threadIdx.x;
    const int wave = tid >> 6;
    const int lane = tid & 63;
    float* row = logits + (size_t)b * SS;

    float4 vals[4];
    float lmax = -1e30f;
    #pragma unroll
    for (int i = 0; i < 4; i++) {
        vals[i] = *(const float4*)(row + (size_t)(i * 256 + tid) * 4);
        lmax = fmaxf(lmax, fmaxf(fmaxf(vals[i].x, vals[i].y), fmaxf(vals[i].z, vals[i].w)));
    }
    #pragma unroll
    for (int off = 32; off >= 1; off >>= 1)
        lmax = fmaxf(lmax, __shfl_xor(lmax, off));

    __shared__ float smax[4], ssum[4];
    if (lane == 0) smax[wave] = lmax;
    __syncthreads();
    const float gmax = fmaxf(fmaxf(smax[0], smax[1]), fmaxf(smax[2], smax[3]));

    float lsum = 0.f;
    #pragma unroll
    for (int i = 0; i < 4; i++) {
        vals[i].x = __expf(vals[i].x - gmax);
        vals[i].y = __expf(vals[i].y - gmax);
        vals[i].z = __expf(vals[i].z - gmax);
        vals[i].w = __expf(vals[i].w - gmax);
        lsum += (vals[i].x + vals[i].y) + (vals[i].z + vals[i].w);
    }
    #pragma unroll
    for (int off = 32; off >= 1; off >>= 1)
        lsum += __shfl_xor(lsum, off);
    if (lane == 0) ssum[wave] = lsum;
    __syncthreads();
    const float total = (ssum[0] + ssum[1]) + (ssum[2] + ssum[3]);
    const float inv = 1.0f / total;

    #pragma unroll
    for (int i = 0; i < 4; i++) {
        float4 o;
        o.x = vals[i].x * inv; o.y = vals[i].y * inv;
        o.z = vals[i].z * inv; o.w = vals[i].w * inv;
        *(float4*)(row + (size_t)(i * 256 + tid) * 4) = o;
    }
}

extern "C" void kernel_launch(void* const* d_in, const int* in_sizes, int n_in,
                              void* d_out, int out_size, void* d_ws, size_t ws_size,
                              hipStream_t stream) {
    const float* hidden   = (const float*)d_in[0];
    const float* seq_embs = (const float*)d_in[1];
    const int*   mask     = (const int*)d_in[2];
    const float* W_attn   = (const float*)d_in[3];
    const float* b_attn   = (const float*)d_in[4];
    const float* v_w      = (const float*)d_in[5];
    float* out = (float*)d_out;

    float*          hproj = (float*)d_ws;                              // 32 KB
    unsigned short* Wb    = (unsigned short*)((char*)d_ws + 32768);    // 32 KB
    float*          vv    = (float*)((char*)d_ws + 65536);             // 512 B

    prep_kernel<<<64, 256, 0, stream>>>(hidden, W_attn, b_attn, v_w, hproj, Wb, vv);
    dim3 grid(SS / 64, BB);
    logits_kernel<<<grid, 256, 0, stream>>>(seq_embs, mask, hproj, Wb, vv, out);
    softmax_kernel<<<BB, 256, 0, stream>>>(out);
}

// Round 2
// 224.140 us; speedup vs baseline: 1.0909x; 1.0909x over previous
//
#include <hip/hip_runtime.h>
#include <hip/hip_bf16.h>

#define BB 64
#define SS 4096
#define EE 128   // EMB_DIM
#define DD 128   // DEC_DIM
#define FAN 256
#define NEG_INF_F (-1e10f)

typedef __bf16 bf16x8 __attribute__((ext_vector_type(8)));
typedef unsigned short u16x8 __attribute__((ext_vector_type(8)));
typedef float f32x4 __attribute__((ext_vector_type(4)));

__device__ inline bf16x8 ld_frag(const unsigned short* p) {
    union { u16x8 u; bf16x8 b; } c;
    c.u = *(const u16x8*)p;
    return c.b;
}

__device__ inline uint2 f4_to_bf4(float4 f) {
    union { __hip_bfloat162 b; unsigned u; } lo, hi;
    lo.b = __float22bfloat162_rn(make_float2(f.x, f.y));
    hi.b = __float22bfloat162_rn(make_float2(f.z, f.w));
    return make_uint2(lo.u, hi.u);
}

__device__ inline float tanh_fast(float x) {
    float ax = fabsf(x);
    float e = __expf(-2.0f * ax);
    float t = (1.0f - e) * __builtin_amdgcn_rcpf(1.0f + e);
    return x < 0.0f ? -t : t;
}

// ---------------------------------------------------------------------------
// Kernel 1: h_proj (fp32) + We -> bf16 conversion + v copy, into workspace.
// grid 64 x 256
// ---------------------------------------------------------------------------
__global__ __launch_bounds__(256) void prep_kernel(
        const float* __restrict__ hidden, const float* __restrict__ W_attn,
        const float* __restrict__ b_attn, const float* __restrict__ v_w,
        float* __restrict__ hproj, unsigned short* __restrict__ Wb,
        float* __restrict__ v_out) {
    const int b = blockIdx.x;
    const int t = threadIdx.x;
    if (t < 128) {
        // h_proj[b][t] = b_attn[t] + hidden[b,:] . W_attn[t, 0:128]
        float acc = b_attn[t];
        const float* hrow = hidden + b * DD;
        const float* wrow = W_attn + t * FAN;
        #pragma unroll 8
        for (int e = 0; e < DD; e++) acc += hrow[e] * wrow[e];
        hproj[b * DD + t] = acc;
        if (b == 0) v_out[t] = v_w[t];
    } else {
        // convert 2 rows of We per block (128 rows over 64 blocks)
        int tt = t - 128;
        int d  = 2 * b + (tt >> 6);
        int e0 = (tt & 63) * 2;
        float2 src = *(const float2*)(W_attn + d * FAN + DD + e0);
        union { __hip_bfloat162 bb; unsigned u; } c;
        c.bb = __float22bfloat162_rn(src);
        *(unsigned*)&Wb[d * EE + e0] = c.u;
    }
}

// ---------------------------------------------------------------------------
// Kernel 2: logits[b][s] = v . tanh(hproj[b] + X[s] @ We^T), masked.
// grid (S/64, B) x 256. Masked s-rows: skip the HBM read entirely.
// Single __syncthreads; mask read straight from global during staging.
// ---------------------------------------------------------------------------
__global__ __launch_bounds__(256) void logits_kernel(
        const float* __restrict__ seq_embs, const int* __restrict__ mask,
        const float* __restrict__ hproj, const unsigned short* __restrict__ Wb,
        const float* __restrict__ v, float* __restrict__ logits) {
    __shared__ __attribute__((aligned(16))) unsigned short Xs[64][136];  // s x e (row 272B, 16B-aligned)
    __shared__ __attribute__((aligned(16))) unsigned short Ws[128][136]; // d x e
    __shared__ int   mrow[64];
    __shared__ float hp_s[128];
    __shared__ float v_s[128];

    const int b   = blockIdx.y;
    const int s0  = blockIdx.x * 64;
    const int tid = threadIdx.x;

    const int* __restrict__ mask_g = mask + (size_t)b * SS + s0;

    // mask values for the 4 X-rows this thread stages (row-uniform per 16 lanes)
    int mk[4];
    #pragma unroll
    for (int k = 0; k < 4; k++) mk[k] = mask_g[(tid + k * 256) >> 4];

    // X tile: 64 rows x 128 e, fp32->bf16, 32B in -> 16B LDS per thread-iter.
    const float* xbase = seq_embs + (size_t)s0 * (BB * EE) + (size_t)b * EE;
    #pragma unroll
    for (int k = 0; k < 4; k++) {
        const int i = tid + k * 256;
        const int s = i >> 4, e8 = i & 15;
        uint4 o = make_uint4(0u, 0u, 0u, 0u);
        if (mk[k] != 0) {
            const float4* src = (const float4*)(xbase + (size_t)s * (BB * EE) + e8 * 8);
            float4 f0 = src[0], f1 = src[1];
            uint2 a = f4_to_bf4(f0), bq = f4_to_bf4(f1);
            o = make_uint4(a.x, a.y, bq.x, bq.y);
        }
        *(uint4*)&Xs[s][e8 * 8] = o;
    }

    // We (bf16 in ws, L2-resident): 16B per thread-iter into LDS [d][e]
    const uint4* __restrict__ Wb16 = (const uint4*)Wb;  // 16 uint4 per d-row
    #pragma unroll
    for (int k = 0; k < 8; k++) {
        const int i = tid + k * 256;
        const int d = i >> 4, e8 = i & 15;
        *(uint4*)&Ws[d][e8 * 8] = Wb16[i];
    }

    // small per-block state
    if (tid < 64) {
        mrow[tid] = mask_g[tid];
    } else if (tid < 192) {
        hp_s[tid - 64] = hproj[b * DD + (tid - 64)];
    } else {
        v_s[tid - 192] = v[tid - 192];
        v_s[tid - 128] = v[tid - 128];
    }
    __syncthreads();

    const int wave = tid >> 6;
    const int lane = tid & 63;
    const int m    = lane & 15;
    const int quad = lane >> 4;

    f32x4 acc[8];
    #pragma unroll
    for (int t = 0; t < 8; t++) acc[t] = (f32x4){0.f, 0.f, 0.f, 0.f};

    const int arow = wave * 16 + m;
    #pragma unroll
    for (int kk = 0; kk < 4; kk++) {
        const int k0 = kk * 32 + quad * 8;
        bf16x8 a = ld_frag(&Xs[arow][k0]);
        #pragma unroll
        for (int t = 0; t < 8; t++) {
            bf16x8 bf = ld_frag(&Ws[t * 16 + m][k0]);
            acc[t] = __builtin_amdgcn_mfma_f32_16x16x32_bf16(a, bf, acc[t], 0, 0, 0);
        }
    }

    // Epilogue: logit[s] = sum_d v[d] * tanh(hp[d] + E[s][d])
    // D layout: row = quad*4 + r (s within wave tile), col = m (d within 16-tile)
    float red[4];
    #pragma unroll
    for (int r = 0; r < 4; r++) {
        float part = 0.f;
        #pragma unroll
        for (int t = 0; t < 8; t++) {
            int d = t * 16 + m;
            part += v_s[d] * tanh_fast(hp_s[d] + acc[t][r]);
        }
        part += __shfl_xor(part, 1);
        part += __shfl_xor(part, 2);
        part += __shfl_xor(part, 4);
        part += __shfl_xor(part, 8);
        red[r] = part;
    }
    if (m == 0) {
        #pragma unroll
        for (int r = 0; r < 4; r++) {
            int sl = wave * 16 + quad * 4 + r;
            float val = (mrow[sl] != 0) ? red[r] : NEG_INF_F;
            logits[(size_t)b * SS + s0 + sl] = val;
        }
    }
}

// ---------------------------------------------------------------------------
// Kernel 3: in-place row softmax over S=4096. grid B x 256.
// ---------------------------------------------------------------------------
__global__ __launch_bounds__(256) void softmax_kernel(float* __restrict__ logits) {
    const int b = blockIdx.x;
    const int tid = threadIdx.x;
    const int wave = tid >> 6;
    const int lane = tid & 63;
    float* row = logits + (size_t)b * SS;

    float4 vals[4];
    float lmax = -1e30f;
    #pragma unroll
    for (int i = 0; i < 4; i++) {
        vals[i] = *(const float4*)(row + (size_t)(i * 256 + tid) * 4);
        lmax = fmaxf(lmax, fmaxf(fmaxf(vals[i].x, vals[i].y), fmaxf(vals[i].z, vals[i].w)));
    }
    #pragma unroll
    for (int off = 32; off >= 1; off >>= 1)
        lmax = fmaxf(lmax, __shfl_xor(lmax, off));

    __shared__ float smax[4], ssum[4];
    if (lane == 0) smax[wave] = lmax;
    __syncthreads();
    const float gmax = fmaxf(fmaxf(smax[0], smax[1]), fmaxf(smax[2], smax[3]));

    float lsum = 0.f;
    #pragma unroll
    for (int i = 0; i < 4; i++) {
        vals[i].x = __expf(vals[i].x - gmax);
        vals[i].y = __expf(vals[i].y - gmax);
        vals[i].z = __expf(vals[i].z - gmax);
        vals[i].w = __expf(vals[i].w - gmax);
        lsum += (vals[i].x + vals[i].y) + (vals[i].z + vals[i].w);
    }
    #pragma unroll
    for (int off = 32; off >= 1; off >>= 1)
        lsum += __shfl_xor(lsum, off);
    if (lane == 0) ssum[wave] = lsum;
    __syncthreads();
    const float total = (ssum[0] + ssum[1]) + (ssum[2] + ssum[3]);
    const float inv = 1.0f / total;

    #pragma unroll
    for (int i = 0; i < 4; i++) {
        float4 o;
        o.x = vals[i].x * inv; o.y = vals[i].y * inv;
        o.z = vals[i].z * inv; o.w = vals[i].w * inv;
        *(float4*)(row + (size_t)(i * 256 + tid) * 4) = o;
    }
}

extern "C" void kernel_launch(void* const* d_in, const int* in_sizes, int n_in,
                              void* d_out, int out_size, void* d_ws, size_t ws_size,
                              hipStream_t stream) {
    const float* hidden   = (const float*)d_in[0];
    const float* seq_embs = (const float*)d_in[1];
    const int*   mask     = (const int*)d_in[2];
    const float* W_attn   = (const float*)d_in[3];
    const float* b_attn   = (const float*)d_in[4];
    const float* v_w      = (const float*)d_in[5];
    float* out = (float*)d_out;

    float*          hproj = (float*)d_ws;                              // 32 KB
    unsigned short* Wb    = (unsigned short*)((char*)d_ws + 32768);    // 32 KB
    float*          vv    = (float*)((char*)d_ws + 65536);             // 512 B

    prep_kernel<<<64, 256, 0, stream>>>(hidden, W_attn, b_attn, v_w, hproj, Wb, vv);
    dim3 grid(SS / 64, BB);
    logits_kernel<<<grid, 256, 0, stream>>>(seq_embs, mask, hproj, Wb, vv, out);
    softmax_kernel<<<BB, 256, 0, stream>>>(out);
}

// Round 3
// 220.911 us; speedup vs baseline: 1.1068x; 1.0146x over previous
//
#include <hip/hip_runtime.h>
#include <hip/hip_bf16.h>

#define BB 64
#define SS 4096
#define EE 128   // EMB_DIM
#define DD 128   // DEC_DIM
#define FAN 256
#define NEG_INF_F (-1e10f)

typedef __bf16 bf16x8 __attribute__((ext_vector_type(8)));
typedef unsigned short u16x8 __attribute__((ext_vector_type(8)));
typedef float f32x4 __attribute__((ext_vector_type(4)));

__device__ inline bf16x8 ld_frag(const unsigned short* p) {
    union { u16x8 u; bf16x8 b; } c;
    c.u = *(const u16x8*)p;
    return c.b;
}

__device__ inline uint2 f4_to_bf4(float4 f) {
    union { __hip_bfloat162 b; unsigned u; } lo, hi;
    lo.b = __float22bfloat162_rn(make_float2(f.x, f.y));
    hi.b = __float22bfloat162_rn(make_float2(f.z, f.w));
    return make_uint2(lo.u, hi.u);
}

__device__ inline float tanh_fast(float x) {
    float ax = fabsf(x);
    float e = __expf(-2.0f * ax);
    float t = (1.0f - e) * __builtin_amdgcn_rcpf(1.0f + e);
    return x < 0.0f ? -t : t;
}

// ---------------------------------------------------------------------------
// Kernel 1: h_proj (fp32) + We -> bf16 conversion + v copy, into workspace.
// grid 64 x 256
// ---------------------------------------------------------------------------
__global__ __launch_bounds__(256) void prep_kernel(
        const float* __restrict__ hidden, const float* __restrict__ W_attn,
        const float* __restrict__ b_attn, const float* __restrict__ v_w,
        float* __restrict__ hproj, unsigned short* __restrict__ Wb,
        float* __restrict__ v_out) {
    const int b = blockIdx.x;
    const int t = threadIdx.x;
    if (t < 128) {
        // h_proj[b][t] = b_attn[t] + hidden[b,:] . W_attn[t, 0:128]
        float acc = b_attn[t];
        const float* hrow = hidden + b * DD;
        const float* wrow = W_attn + t * FAN;
        #pragma unroll 8
        for (int e = 0; e < DD; e++) acc += hrow[e] * wrow[e];
        hproj[b * DD + t] = acc;
        if (b == 0) v_out[t] = v_w[t];
    } else {
        // convert 2 rows of We per block (128 rows over 64 blocks)
        int tt = t - 128;
        int d  = 2 * b + (tt >> 6);
        int e0 = (tt & 63) * 2;
        float2 src = *(const float2*)(W_attn + d * FAN + DD + e0);
        union { __hip_bfloat162 bb; unsigned u; } c;
        c.bb = __float22bfloat162_rn(src);
        *(unsigned*)&Wb[d * EE + e0] = c.u;
    }
}

// ---------------------------------------------------------------------------
// Kernel 2: logits[b][s] = v . tanh(hproj[b] + X[s] @ We^T), masked.
// grid (S/64, B) x 256. Masked s-rows: HBM read skipped via exec mask.
// A-frags loaded global->register directly (no X LDS tile); only Ws in LDS.
// ---------------------------------------------------------------------------
__global__ __launch_bounds__(256) void logits_kernel(
        const float* __restrict__ seq_embs, const int* __restrict__ mask,
        const float* __restrict__ hproj, const unsigned short* __restrict__ Wb,
        const float* __restrict__ v, float* __restrict__ logits) {
    __shared__ __attribute__((aligned(16))) unsigned short Ws[128][136]; // d x e, pad->conflict-free

    const int b    = blockIdx.y;
    const int s0   = blockIdx.x * 64;
    const int tid  = threadIdx.x;
    const int wave = tid >> 6;
    const int lane = tid & 63;
    const int m    = lane & 15;
    const int quad = lane >> 4;

    const int* __restrict__ mask_g = mask + (size_t)b * SS + s0;

    // --- A-frags direct from global, fp32->bf16 in-register; masked rows -> 0.
    // A layout: lane(m,quad) holds A[m][quad*8 + j] per K=32 slice kk.
    const int arow = wave * 16 + m;
    const int am   = mask_g[arow];
    const float* xrow = seq_embs + (size_t)(s0 + arow) * (BB * EE)
                      + (size_t)b * EE + quad * 8;
    bf16x8 afrag[4];
    #pragma unroll
    for (int kk = 0; kk < 4; kk++) {
        union { uint4 q; bf16x8 bf; } c;
        c.q = make_uint4(0u, 0u, 0u, 0u);
        if (am != 0) {
            float4 f0 = *(const float4*)(xrow + kk * 32);
            float4 f1 = *(const float4*)(xrow + kk * 32 + 4);
            uint2 a = f4_to_bf4(f0), bq = f4_to_bf4(f1);
            c.q = make_uint4(a.x, a.y, bq.x, bq.y);
        }
        afrag[kk] = c.bf;
    }

    // --- Stage We (bf16, L2-resident ws) into LDS: 16B per thread-iter.
    const uint4* __restrict__ Wb16 = (const uint4*)Wb;  // 16 uint4 per d-row
    #pragma unroll
    for (int k = 0; k < 8; k++) {
        const int i = tid + k * 256;
        const int d = i >> 4, e8 = i & 15;
        *(uint4*)&Ws[d][e8 * 8] = Wb16[i];
    }
    __syncthreads();

    // --- MFMA: 64 s-rows x 128 d, K=128
    f32x4 acc[8];
    #pragma unroll
    for (int t = 0; t < 8; t++) acc[t] = (f32x4){0.f, 0.f, 0.f, 0.f};
    #pragma unroll
    for (int kk = 0; kk < 4; kk++) {
        const int k0 = kk * 32 + quad * 8;
        #pragma unroll
        for (int t = 0; t < 8; t++) {
            bf16x8 bf = ld_frag(&Ws[t * 16 + m][k0]);
            acc[t] = __builtin_amdgcn_mfma_f32_16x16x32_bf16(afrag[kk], bf, acc[t], 0, 0, 0);
        }
    }

    // --- Epilogue: logit[s] = sum_d v[d] * tanh(hp[d] + E[s][d])
    // D layout: row = quad*4 + r (s within wave tile), col = m (d within 16-tile)
    float hp_r[8], v_r[8];
    #pragma unroll
    for (int t = 0; t < 8; t++) {
        hp_r[t] = hproj[b * DD + t * 16 + m];
        v_r[t]  = v[t * 16 + m];
    }
    const int4 mq = *(const int4*)(mask_g + wave * 16 + quad * 4);
    const int mqa[4] = {mq.x, mq.y, mq.z, mq.w};

    float red[4];
    #pragma unroll
    for (int r = 0; r < 4; r++) {
        float part = 0.f;
        if (mqa[r] != 0) {   // uniform across the 16-lane m-group: shfl-safe
            #pragma unroll
            for (int t = 0; t < 8; t++)
                part += v_r[t] * tanh_fast(hp_r[t] + acc[t][r]);
            part += __shfl_xor(part, 1);
            part += __shfl_xor(part, 2);
            part += __shfl_xor(part, 4);
            part += __shfl_xor(part, 8);
        }
        red[r] = (mqa[r] != 0) ? part : NEG_INF_F;
    }
    if (m == 0) {
        float4 o = make_float4(red[0], red[1], red[2], red[3]);
        *(float4*)&logits[(size_t)b * SS + s0 + wave * 16 + quad * 4] = o;
    }
}

// ---------------------------------------------------------------------------
// Kernel 3: in-place row softmax over S=4096. grid B x 256.
// ---------------------------------------------------------------------------
__global__ __launch_bounds__(256) void softmax_kernel(float* __restrict__ logits) {
    const int b = blockIdx.x;
    const int tid = threadIdx.x;
    const int wave = tid >> 6;
    const int lane = tid & 63;
    float* row = logits + (size_t)b * SS;

    float4 vals[4];
    float lmax = -1e30f;
    #pragma unroll
    for (int i = 0; i < 4; i++) {
        vals[i] = *(const float4*)(row + (size_t)(i * 256 + tid) * 4);
        lmax = fmaxf(lmax, fmaxf(fmaxf(vals[i].x, vals[i].y), fmaxf(vals[i].z, vals[i].w)));
    }
    #pragma unroll
    for (int off = 32; off >= 1; off >>= 1)
        lmax = fmaxf(lmax, __shfl_xor(lmax, off));

    __shared__ float smax[4], ssum[4];
    if (lane == 0) smax[wave] = lmax;
    __syncthreads();
    const float gmax = fmaxf(fmaxf(smax[0], smax[1]), fmaxf(smax[2], smax[3]));

    float lsum = 0.f;
    #pragma unroll
    for (int i = 0; i < 4; i++) {
        vals[i].x = __expf(vals[i].x - gmax);
        vals[i].y = __expf(vals[i].y - gmax);
        vals[i].z = __expf(vals[i].z - gmax);
        vals[i].w = __expf(vals[i].w - gmax);
        lsum += (vals[i].x + vals[i].y) + (vals[i].z + vals[i].w);
    }
    #pragma unroll
    for (int off = 32; off >= 1; off >>= 1)
        lsum += __shfl_xor(lsum, off);
    if (lane == 0) ssum[wave] = lsum;
    __syncthreads();
    const float total = (ssum[0] + ssum[1]) + (ssum[2] + ssum[3]);
    const float inv = 1.0f / total;

    #pragma unroll
    for (int i = 0; i < 4; i++) {
        float4 o;
        o.x = vals[i].x * inv; o.y = vals[i].y * inv;
        o.z = vals[i].z * inv; o.w = vals[i].w * inv;
        *(float4*)(row + (size_t)(i * 256 + tid) * 4) = o;
    }
}

extern "C" void kernel_launch(void* const* d_in, const int* in_sizes, int n_in,
                              void* d_out, int out_size, void* d_ws, size_t ws_size,
                              hipStream_t stream) {
    const float* hidden   = (const float*)d_in[0];
    const float* seq_embs = (const float*)d_in[1];
    const int*   mask     = (const int*)d_in[2];
    const float* W_attn   = (const float*)d_in[3];
    const float* b_attn   = (const float*)d_in[4];
    const float* v_w      = (const float*)d_in[5];
    float* out = (float*)d_out;

    float*          hproj = (float*)d_ws;                              // 32 KB
    unsigned short* Wb    = (unsigned short*)((char*)d_ws + 32768);    // 32 KB
    float*          vv    = (float*)((char*)d_ws + 65536);             // 512 B

    prep_kernel<<<64, 256, 0, stream>>>(hidden, W_attn, b_attn, v_w, hproj, Wb, vv);
    dim3 grid(SS / 64, BB);
    logits_kernel<<<grid, 256, 0, stream>>>(seq_embs, mask, hproj, Wb, vv, out);
    softmax_kernel<<<BB, 256, 0, stream>>>(out);
}